// Round 4
// baseline (306.407 us; speedup 1.0000x reference)
//
#include <hip/hip_runtime.h>

#define N 768
#define E 24576

// ---------------------------------------------------------------------------
// Transpose mtr [i][j][8] -> mtrT [j][i][8] so the contraction reads rows.
// ---------------------------------------------------------------------------
__global__ __launch_bounds__(256) void transpose_mtr(
    const float* __restrict__ mtr, float* __restrict__ mtrT) {
  __shared__ float lds[16][16 * 8 + 4];
  const int r = threadIdx.x >> 4;  // 0..15
  const int c = threadIdx.x & 15;  // 0..15
  const size_t i0 = (size_t)blockIdx.y * 16;
  const size_t j0 = (size_t)blockIdx.x * 16;

  const float4* src = (const float4*)(mtr + ((i0 + r) * N + (j0 + c)) * 8);
  float4 a = src[0], b = src[1];
  *(float4*)&lds[r][c * 8 + 0] = a;
  *(float4*)&lds[r][c * 8 + 4] = b;
  __syncthreads();
  float4* dst = (float4*)(mtrT + ((j0 + r) * N + (i0 + c)) * 8);
  dst[0] = *(float4*)&lds[c][r * 8 + 0];
  dst[1] = *(float4*)&lds[c][r * 8 + 4];
}

// ---------------------------------------------------------------------------
// Pre-pass: winner marking (last-write-wins .set semantics) + dst-degree.
// ---------------------------------------------------------------------------
__global__ __launch_bounds__(256) void edge_prep(
    const int* __restrict__ ei, int* __restrict__ winner,
    int* __restrict__ deg) {
  const int e = blockIdx.x * 256 + threadIdx.x;
  if (e >= E) return;
  const int s = ei[e];
  const int d = ei[E + e];
  atomicMax(&winner[(size_t)s * N + d], e);
  atomicAdd(&deg[d], 1);
}

// ---------------------------------------------------------------------------
// Inclusive scan of deg -> offs. One block of N threads.
// ---------------------------------------------------------------------------
__global__ void scan_offs(const int* __restrict__ deg, int* __restrict__ offs) {
  __shared__ int s[N];
  const int t = threadIdx.x;
  s[t] = deg[t];
  __syncthreads();
#pragma unroll 1
  for (int d = 1; d < N; d <<= 1) {
    int v = (t >= d) ? s[t - d] : 0;
    __syncthreads();
    s[t] += v;
    __syncthreads();
  }
  offs[t + 1] = s[t];
  if (t == 0) offs[0] = 0;
}

// ---------------------------------------------------------------------------
// Assign CSR slots to WINNING edges: epos[e] = slot (or -1), jlist[slot] = src.
// ---------------------------------------------------------------------------
__global__ __launch_bounds__(256) void scatter_pos(
    const int* __restrict__ ei, const int* __restrict__ winner,
    const int* __restrict__ offs, int* __restrict__ curs,
    int* __restrict__ jlist, int* __restrict__ epos) {
  const int e = blockIdx.x * 256 + threadIdx.x;
  if (e >= E) return;
  const int s = ei[e];
  const int d = ei[E + e];
  if (winner[(size_t)s * N + d] != e) { epos[e] = -1; return; }
  const int pos = offs[d] + atomicAdd(&curs[d], 1);
  jlist[pos] = s;
  epos[e] = pos;
}

// ---------------------------------------------------------------------------
// Edge MLP: 20 -> 32 -> 32 -> 32 -> 64. Winners write their 8x8 block
// directly into CSR order (Mlist[pos]); losers skip the MLP entirely.
// ---------------------------------------------------------------------------
__global__ __launch_bounds__(256) void edge_mlp(
    const float* __restrict__ feat, const int* __restrict__ ei,
    const float* __restrict__ ea, const int* __restrict__ epos,
    const float* __restrict__ w0, const float* __restrict__ b0,
    const float* __restrict__ w1, const float* __restrict__ b1,
    const float* __restrict__ w2, const float* __restrict__ b2,
    const float* __restrict__ w3, const float* __restrict__ b3,
    float* __restrict__ Mlist) {
  const int e = blockIdx.x * 256 + threadIdx.x;
  if (e >= E) return;
  const int pos = epos[e];
  if (pos < 0) return;
  const int s = ei[e];
  const int d = ei[E + e];

  float x[20];
  {
    float4 t = *(const float4*)(ea + (size_t)e * 4);
    x[0] = t.x; x[1] = t.y; x[2] = t.z; x[3] = t.w;
    float4 f0 = *(const float4*)(feat + (size_t)s * 8);
    float4 f1 = *(const float4*)(feat + (size_t)s * 8 + 4);
    x[4] = f0.x; x[5] = f0.y; x[6] = f0.z; x[7] = f0.w;
    x[8] = f1.x; x[9] = f1.y; x[10] = f1.z; x[11] = f1.w;
    float4 g0 = *(const float4*)(feat + (size_t)d * 8);
    float4 g1 = *(const float4*)(feat + (size_t)d * 8 + 4);
    x[12] = g0.x; x[13] = g0.y; x[14] = g0.z; x[15] = g0.w;
    x[16] = g1.x; x[17] = g1.y; x[18] = g1.z; x[19] = g1.w;
  }

  float h[32];
#pragma unroll
  for (int o = 0; o < 32; ++o) {
    float acc = b0[o];
#pragma unroll
    for (int c = 0; c < 20; ++c) acc = fmaf(w0[o * 20 + c], x[c], acc);
    h[o] = fmaxf(acc, 0.f);
  }

#pragma unroll 1
  for (int l = 0; l < 2; ++l) {
    const float* W = l ? w2 : w1;
    const float* B = l ? b2 : b1;
    float g[32];
#pragma unroll
    for (int o = 0; o < 32; ++o) {
      float acc = B[o];
#pragma unroll
      for (int c = 0; c < 32; ++c) acc = fmaf(W[o * 32 + c], h[c], acc);
      g[o] = fmaxf(acc, 0.f);
    }
#pragma unroll
    for (int o = 0; o < 32; ++o) h[o] = g[o];
  }

  float* erow = Mlist + (size_t)pos * 64;
#pragma unroll
  for (int o4 = 0; o4 < 16; ++o4) {
    float r[4];
#pragma unroll
    for (int q = 0; q < 4; ++q) {
      const int o = o4 * 4 + q;
      float acc = b3[o];
#pragma unroll
      for (int c = 0; c < 32; ++c) acc = fmaf(w3[o * 32 + c], h[c], acc);
      r[q] = acc;
    }
    *(float4*)(erow + o4 * 4) = make_float4(r[0], r[1], r[2], r[3]);
  }
}

// ---------------------------------------------------------------------------
// Walk contraction v4.
// WT[k][i][t] = (1/8) * sum_{slots of k, c} mtrT[j][i][c] * Mlist[slot][c*8+t]
// Wave = one k x 64 i's. 12 i-tiles x 192 k-groups = 2304 blocks, XCD-chunked.
// M address is a pure function of the loop counter (uniform -> s_load,
// no memory dependence); j comes from a preloaded register via readlane.
// ---------------------------------------------------------------------------
__global__ __launch_bounds__(256) void contract4(
    const float* __restrict__ mtrT, const float* __restrict__ Mlist,
    const int* __restrict__ jlist, const int* __restrict__ offs,
    const int* __restrict__ wcnt, float* __restrict__ WT) {
  const int b = blockIdx.x;
  const int x = b & 7;
  const int m = b >> 3;
  int t, kg;
  if (m < 192) { t = x; kg = m; }
  else { t = 8 + (x & 3); kg = (m - 192) * 2 + (x >> 2); }

  const int wave = threadIdx.x >> 6;
  const int lane = threadIdx.x & 63;
  const int k = kg * 4 + wave;
  const int i = t * 64 + lane;

  float acc[8];
#pragma unroll
  for (int q = 0; q < 8; ++q) acc[q] = 0.f;

  const int base = offs[k];
  const int cnt = wcnt[k];

#pragma unroll 1
  for (int cb = 0; cb < cnt; cb += 64) {
    const int rem = min(64, cnt - cb);
    const int jv = (lane < rem) ? jlist[base + cb + lane] : 0;

#pragma unroll 2
    for (int xx = 0; xx < rem; ++xx) {
      const int j = __builtin_amdgcn_readlane(jv, xx);

      const float* P = mtrT + ((size_t)j * N + i) * 8;
      float4 a = ((const float4*)P)[0];
      float4 bb = ((const float4*)P)[1];
      float v[8] = {a.x, a.y, a.z, a.w, bb.x, bb.y, bb.z, bb.w};

      const float* M = Mlist + (size_t)(base + cb + xx) * 64;  // uniform
      float mm[64];
#pragma unroll
      for (int z = 0; z < 16; ++z) {
        float4 q = ((const float4*)M)[z];
        mm[z * 4 + 0] = q.x; mm[z * 4 + 1] = q.y;
        mm[z * 4 + 2] = q.z; mm[z * 4 + 3] = q.w;
      }

#pragma unroll
      for (int c = 0; c < 8; ++c)
#pragma unroll
        for (int tt = 0; tt < 8; ++tt)
          acc[tt] = fmaf(v[c], mm[c * 8 + tt], acc[tt]);
    }
  }

  float* dst = WT + ((size_t)k * N + i) * 8;
  *(float4*)(dst + 0) = make_float4(acc[0] * 0.125f, acc[1] * 0.125f,
                                    acc[2] * 0.125f, acc[3] * 0.125f);
  *(float4*)(dst + 4) = make_float4(acc[4] * 0.125f, acc[5] * 0.125f,
                                    acc[6] * 0.125f, acc[7] * 0.125f);
}

// ---------------------------------------------------------------------------
// Per-node precompute for out_mlp layer 0.
// ---------------------------------------------------------------------------
__global__ __launch_bounds__(256) void node_pre(
    const float* __restrict__ feat, const float* __restrict__ w0,
    const float* __restrict__ b0, float* __restrict__ preK,
    float* __restrict__ preI) {
  const int n = blockIdx.x * 256 + threadIdx.x;
  if (n >= N) return;
  float f[8];
  float4 f0 = ((const float4*)(feat + (size_t)n * 8))[0];
  float4 f1 = ((const float4*)(feat + (size_t)n * 8))[1];
  f[0] = f0.x; f[1] = f0.y; f[2] = f0.z; f[3] = f0.w;
  f[4] = f1.x; f[5] = f1.y; f[6] = f1.z; f[7] = f1.w;
#pragma unroll
  for (int o = 0; o < 32; ++o) {
    float sK = 0.f, sI = b0[o];
#pragma unroll
    for (int c = 0; c < 8; ++c) {
      sK = fmaf(w0[o * 33 + 16 + c], f[c], sK);
      sI = fmaf(w0[o * 33 + 24 + c], f[c], sI);
    }
    preK[n * 32 + o] = sK;
    preI[n * 32 + o] = sI;
  }
}

// ---------------------------------------------------------------------------
// Output MLP: x = [mtr1[i,k,:], mtr1[k,i,:], feat[k], feat[i], (i==k)]
// layer0 uses precomputed node partials; 16x16 (i,k) tile per block.
// ---------------------------------------------------------------------------
__global__ __launch_bounds__(256) void out_mlp(
    const float* __restrict__ mtr, const float* __restrict__ WT,
    const float* __restrict__ preK, const float* __restrict__ preI,
    const float* __restrict__ w0,
    const float* __restrict__ w1, const float* __restrict__ b1,
    const float* __restrict__ w2, const float* __restrict__ b2,
    const float* __restrict__ w3, const float* __restrict__ b3,
    float* __restrict__ out) {
  __shared__ float sK[16][33], sI[16][33];
  const int il = threadIdx.x & 15;
  const int kl = threadIdx.x >> 4;
  const int i = blockIdx.y * 16 + il;
  const int k = blockIdx.x * 16 + kl;

  {
    const int r = threadIdx.x >> 4;
    const int c2 = (threadIdx.x & 15) * 2;
    const float* gK = preK + ((size_t)blockIdx.x * 16 + r) * 32;
    const float* gI = preI + ((size_t)blockIdx.y * 16 + r) * 32;
    sK[r][c2] = gK[c2]; sK[r][c2 + 1] = gK[c2 + 1];
    sI[r][c2] = gI[c2]; sI[r][c2 + 1] = gI[c2 + 1];
  }
  __syncthreads();

  float x[16];
  {
    const float* p1 = WT + ((size_t)k * N + i) * 8;  // mtr1[i,k,:]
    const float* p2 = WT + ((size_t)i * N + k) * 8;  // mtr1[k,i,:]
    float4 a0 = ((const float4*)p1)[0], a1 = ((const float4*)p1)[1];
    float4 c0 = ((const float4*)p2)[0], c1 = ((const float4*)p2)[1];
    x[0] = a0.x; x[1] = a0.y; x[2] = a0.z; x[3] = a0.w;
    x[4] = a1.x; x[5] = a1.y; x[6] = a1.z; x[7] = a1.w;
    x[8] = c0.x; x[9] = c0.y; x[10] = c0.z; x[11] = c0.w;
    x[12] = c1.x; x[13] = c1.y; x[14] = c1.z; x[15] = c1.w;
  }
  const float eye = (i == k) ? 1.f : 0.f;

  float h[32];
#pragma unroll
  for (int o = 0; o < 32; ++o) {
    float acc = sK[kl][o] + sI[il][o];
    acc = fmaf(eye, w0[o * 33 + 32], acc);
#pragma unroll
    for (int c = 0; c < 16; ++c) acc = fmaf(w0[o * 33 + c], x[c], acc);
    h[o] = fmaxf(acc, 0.f);
  }

#pragma unroll 1
  for (int l = 0; l < 2; ++l) {
    const float* W = l ? w2 : w1;
    const float* B = l ? b2 : b1;
    float g[32];
#pragma unroll
    for (int o = 0; o < 32; ++o) {
      float acc = B[o];
#pragma unroll
      for (int c = 0; c < 32; ++c) acc = fmaf(W[o * 32 + c], h[c], acc);
      g[o] = fmaxf(acc, 0.f);
    }
#pragma unroll
    for (int o = 0; o < 32; ++o) h[o] = g[o];
  }

  const size_t idx = ((size_t)i * N + k) * 8;
  float r[8];
#pragma unroll
  for (int t = 0; t < 8; ++t) {
    float acc = b3[t];
#pragma unroll
    for (int c = 0; c < 32; ++c) acc = fmaf(w3[t * 32 + c], h[c], acc);
    r[t] = acc;
  }
  *(float4*)(out + idx + 0) = make_float4(mtr[idx + 0] + r[0], mtr[idx + 1] + r[1],
                                          mtr[idx + 2] + r[2], mtr[idx + 3] + r[3]);
  *(float4*)(out + idx + 4) = make_float4(mtr[idx + 4] + r[4], mtr[idx + 5] + r[5],
                                          mtr[idx + 6] + r[6], mtr[idx + 7] + r[7]);
}

// ---------------------------------------------------------------------------
extern "C" void kernel_launch(void* const* d_in, const int* in_sizes, int n_in,
                              void* d_out, int out_size, void* d_ws,
                              size_t ws_size, hipStream_t stream) {
  const float* mtr  = (const float*)d_in[0];
  const float* feat = (const float*)d_in[1];
  const int*   ei   = (const int*)d_in[2];
  const float* ea   = (const float*)d_in[3];
  const float* ew0 = (const float*)d_in[4];
  const float* eb0 = (const float*)d_in[5];
  const float* ew1 = (const float*)d_in[6];
  const float* eb1 = (const float*)d_in[7];
  const float* ew2 = (const float*)d_in[8];
  const float* eb2 = (const float*)d_in[9];
  const float* ew3 = (const float*)d_in[10];
  const float* eb3 = (const float*)d_in[11];
  const float* ow0 = (const float*)d_in[12];
  const float* ob0 = (const float*)d_in[13];
  const float* ow1 = (const float*)d_in[14];
  const float* ob1 = (const float*)d_in[15];
  const float* ow2 = (const float*)d_in[16];
  const float* ob2 = (const float*)d_in[17];
  const float* ow3 = (const float*)d_in[18];
  const float* ob3 = (const float*)d_in[19];
  float* out = (float*)d_out;

  char* ws = (char*)d_ws;
  float* Mlist = (float*)ws; ws += (size_t)E * 64 * 4;       // 6.29 MB
  float* mtrT  = (float*)ws; ws += (size_t)N * N * 8 * 4;    // 18.87 MB
  float* WT    = (float*)ws; ws += (size_t)N * N * 8 * 4;    // 18.87 MB
  int* winner  = (int*)ws;   ws += (size_t)N * N * 4;        // 2.36 MB
  int* deg     = (int*)ws;   ws += 1024 * 4;
  int* offs    = (int*)ws;   ws += 1024 * 4;
  int* curs    = (int*)ws;   ws += 1024 * 4;
  int* jlist   = (int*)ws;   ws += (size_t)E * 4;            // 98 KB
  int* epos    = (int*)ws;   ws += (size_t)E * 4;            // 98 KB
  float* preK  = (float*)ws; ws += (size_t)N * 32 * 4;       // 98 KB
  float* preI  = (float*)ws; ws += (size_t)N * 32 * 4;       // 98 KB

  hipMemsetAsync(winner, 0xFF, (size_t)N * N * 4, stream);  // -1
  hipMemsetAsync(deg, 0, 1024 * 4, stream);
  hipMemsetAsync(curs, 0, 1024 * 4, stream);

  edge_prep<<<E / 256, 256, 0, stream>>>(ei, winner, deg);
  scan_offs<<<1, N, 0, stream>>>(deg, offs);
  scatter_pos<<<E / 256, 256, 0, stream>>>(ei, winner, offs, curs, jlist, epos);
  transpose_mtr<<<dim3(48, 48), 256, 0, stream>>>(mtr, mtrT);
  node_pre<<<3, 256, 0, stream>>>(feat, ow0, ob0, preK, preI);
  edge_mlp<<<E / 256, 256, 0, stream>>>(feat, ei, ea, epos, ew0, eb0, ew1, eb1,
                                        ew2, eb2, ew3, eb3, Mlist);
  contract4<<<2304, 256, 0, stream>>>(mtrT, Mlist, jlist, offs, curs, WT);
  out_mlp<<<dim3(48, 48), 256, 0, stream>>>(mtr, WT, preK, preI, ow0, ow1, ob1,
                                            ow2, ob2, ow3, ob3, out);
}

// Round 5
// 191.131 us; speedup vs baseline: 1.6031x; 1.6031x over previous
//
#include <hip/hip_runtime.h>

#define N 768
#define E 24576
#define CH 8             // edges per staged LDS chunk
#define CHF (CH * 64)    // floats per chunk (512 = 2 KB)

// ---------------------------------------------------------------------------
// Transpose mtr [i][j][8] -> mtrT [j][i][8] so the contraction reads rows.
// ---------------------------------------------------------------------------
__global__ __launch_bounds__(256) void transpose_mtr(
    const float* __restrict__ mtr, float* __restrict__ mtrT) {
  __shared__ float lds[16][16 * 8 + 4];
  const int r = threadIdx.x >> 4;  // 0..15
  const int c = threadIdx.x & 15;  // 0..15
  const size_t i0 = (size_t)blockIdx.y * 16;
  const size_t j0 = (size_t)blockIdx.x * 16;

  const float4* src = (const float4*)(mtr + ((i0 + r) * N + (j0 + c)) * 8);
  float4 a = src[0], b = src[1];
  *(float4*)&lds[r][c * 8 + 0] = a;
  *(float4*)&lds[r][c * 8 + 4] = b;
  __syncthreads();
  float4* dst = (float4*)(mtrT + ((j0 + r) * N + (i0 + c)) * 8);
  dst[0] = *(float4*)&lds[c][r * 8 + 0];
  dst[1] = *(float4*)&lds[c][r * 8 + 4];
}

// ---------------------------------------------------------------------------
// Pre-pass: winner marking (last-write-wins .set semantics) + dst-degree.
// ---------------------------------------------------------------------------
__global__ __launch_bounds__(256) void edge_prep(
    const int* __restrict__ ei, int* __restrict__ winner,
    int* __restrict__ deg) {
  const int e = blockIdx.x * 256 + threadIdx.x;
  if (e >= E) return;
  const int s = ei[e];
  const int d = ei[E + e];
  atomicMax(&winner[(size_t)s * N + d], e);
  atomicAdd(&deg[d], 1);
}

// ---------------------------------------------------------------------------
// Inclusive scan of deg -> offs. One block of N threads.
// ---------------------------------------------------------------------------
__global__ void scan_offs(const int* __restrict__ deg, int* __restrict__ offs) {
  __shared__ int s[N];
  const int t = threadIdx.x;
  s[t] = deg[t];
  __syncthreads();
#pragma unroll 1
  for (int d = 1; d < N; d <<= 1) {
    int v = (t >= d) ? s[t - d] : 0;
    __syncthreads();
    s[t] += v;
    __syncthreads();
  }
  offs[t + 1] = s[t];
  if (t == 0) offs[0] = 0;
}

// ---------------------------------------------------------------------------
// Assign CSR slots to WINNING edges: epos[e] = slot (or -1), jlist[slot] = src.
// ---------------------------------------------------------------------------
__global__ __launch_bounds__(256) void scatter_pos(
    const int* __restrict__ ei, const int* __restrict__ winner,
    const int* __restrict__ offs, int* __restrict__ curs,
    int* __restrict__ jlist, int* __restrict__ epos) {
  const int e = blockIdx.x * 256 + threadIdx.x;
  if (e >= E) return;
  const int s = ei[e];
  const int d = ei[E + e];
  if (winner[(size_t)s * N + d] != e) { epos[e] = -1; return; }
  const int pos = offs[d] + atomicAdd(&curs[d], 1);
  jlist[pos] = s;
  epos[e] = pos;
}

// ---------------------------------------------------------------------------
// Edge MLP: 20 -> 32 -> 32 -> 32 -> 64. Winners write their 8x8 block
// directly into CSR order (Mlist[pos]); losers skip the MLP entirely.
// ---------------------------------------------------------------------------
__global__ __launch_bounds__(256) void edge_mlp(
    const float* __restrict__ feat, const int* __restrict__ ei,
    const float* __restrict__ ea, const int* __restrict__ epos,
    const float* __restrict__ w0, const float* __restrict__ b0,
    const float* __restrict__ w1, const float* __restrict__ b1,
    const float* __restrict__ w2, const float* __restrict__ b2,
    const float* __restrict__ w3, const float* __restrict__ b3,
    float* __restrict__ Mlist) {
  const int e = blockIdx.x * 256 + threadIdx.x;
  if (e >= E) return;
  const int pos = epos[e];
  if (pos < 0) return;
  const int s = ei[e];
  const int d = ei[E + e];

  float x[20];
  {
    float4 t = *(const float4*)(ea + (size_t)e * 4);
    x[0] = t.x; x[1] = t.y; x[2] = t.z; x[3] = t.w;
    float4 f0 = *(const float4*)(feat + (size_t)s * 8);
    float4 f1 = *(const float4*)(feat + (size_t)s * 8 + 4);
    x[4] = f0.x; x[5] = f0.y; x[6] = f0.z; x[7] = f0.w;
    x[8] = f1.x; x[9] = f1.y; x[10] = f1.z; x[11] = f1.w;
    float4 g0 = *(const float4*)(feat + (size_t)d * 8);
    float4 g1 = *(const float4*)(feat + (size_t)d * 8 + 4);
    x[12] = g0.x; x[13] = g0.y; x[14] = g0.z; x[15] = g0.w;
    x[16] = g1.x; x[17] = g1.y; x[18] = g1.z; x[19] = g1.w;
  }

  float h[32];
#pragma unroll
  for (int o = 0; o < 32; ++o) {
    float acc = b0[o];
#pragma unroll
    for (int c = 0; c < 20; ++c) acc = fmaf(w0[o * 20 + c], x[c], acc);
    h[o] = fmaxf(acc, 0.f);
  }

#pragma unroll 1
  for (int l = 0; l < 2; ++l) {
    const float* W = l ? w2 : w1;
    const float* B = l ? b2 : b1;
    float g[32];
#pragma unroll
    for (int o = 0; o < 32; ++o) {
      float acc = B[o];
#pragma unroll
      for (int c = 0; c < 32; ++c) acc = fmaf(W[o * 32 + c], h[c], acc);
      g[o] = fmaxf(acc, 0.f);
    }
#pragma unroll
    for (int o = 0; o < 32; ++o) h[o] = g[o];
  }

  float* erow = Mlist + (size_t)pos * 64;
#pragma unroll
  for (int o4 = 0; o4 < 16; ++o4) {
    float r[4];
#pragma unroll
    for (int q = 0; q < 4; ++q) {
      const int o = o4 * 4 + q;
      float acc = b3[o];
#pragma unroll
      for (int c = 0; c < 32; ++c) acc = fmaf(w3[o * 32 + c], h[c], acc);
      r[q] = acc;
    }
    *(float4*)(erow + o4 * 4) = make_float4(r[0], r[1], r[2], r[3]);
  }
}

// ---------------------------------------------------------------------------
// Walk contraction v5 — LDS-staged M stream (global_load_lds, double-buffered).
// WT[k][i][t] = (1/8) * sum_{slots of k, c} mtrT[j][i][c] * Mlist[slot][c*8+t]
// Block = 1 k x 128 i's (128 threads). 6 i-tiles x 768 k = 4608 blocks,
// XCD-chunked (per-XCD mtrT slab 3.1 MB fits the 4 MB L2).
// M read from LDS via broadcast ds_read (no divergence-analysis dependence);
// j from preloaded register via readlane; only P-loads touch L2 per edge.
// ---------------------------------------------------------------------------
__device__ __forceinline__ void gload_lds16(const float* g, float* l) {
  __builtin_amdgcn_global_load_lds(
      (const __attribute__((address_space(1))) unsigned int*)g,
      (__attribute__((address_space(3))) unsigned int*)l, 16, 0, 0);
}

__global__ __launch_bounds__(128) void contract5(
    const float* __restrict__ mtrT, const float* __restrict__ Mlist,
    const int* __restrict__ jlist, const int* __restrict__ offs,
    const int* __restrict__ wcnt, float* __restrict__ WT) {
  __shared__ __align__(16) float Ms[2][CHF];

  const int b = blockIdx.x;
  const int g = (b & 7) * 576 + (b >> 3);  // XCD-chunked: 4608 = 8 x 576
  const int t = g / 768;                   // i-tile 0..5
  const int k = g % 768;
  const int tid = threadIdx.x;             // 0..127
  const int lane = tid & 63;
  const int i = t * 128 + tid;

  const int base = offs[k];
  const int cnt = wcnt[k];
  const int nch = (cnt + CH - 1) / CH;

  float acc[8];
#pragma unroll
  for (int q = 0; q < 8; ++q) acc[q] = 0.f;

  // STAGE(ch): stage edges [ch*CH, ch*CH+CH) of this k into Ms[ch&1].
  // Thread tid stages the 16B slice (tid&15) of edge ch*CH+(tid>>4).
  // LDS dest is wave-uniform base + lane*16 (global_load_lds semantics).
#define STAGE(ch_)                                                          \
  do {                                                                      \
    const int _c = (ch_);                                                   \
    if (_c * CH + (tid >> 4) < cnt) {                                       \
      const float* _g = Mlist + ((size_t)(base + _c * CH) * 64) + tid * 4;  \
      float* _l = &Ms[_c & 1][(tid >> 6) * 256];                            \
      gload_lds16(_g, _l);                                                  \
    }                                                                       \
  } while (0)

  if (nch > 0) STAGE(0);
  __syncthreads();

  int jv = 0;
#pragma unroll 1
  for (int ch = 0; ch < nch; ++ch) {
    if ((ch & 7) == 0) {  // refresh 64 j's per super-chunk
      const int o = ch * CH + lane;
      jv = (o < cnt) ? jlist[base + o] : 0;
    }
    if (ch + 1 < nch) STAGE(ch + 1);

    const float* Mb = &Ms[ch & 1][0];
    const int lim = min(CH, cnt - ch * CH);
#pragma unroll 2
    for (int q = 0; q < lim; ++q) {
      const int xx = ch * CH + q;
      const int j = __builtin_amdgcn_readlane(jv, xx & 63);

      const float* P = mtrT + ((size_t)j * N + i) * 8;
      float4 a = ((const float4*)P)[0];
      float4 bb = ((const float4*)P)[1];
      float v[8] = {a.x, a.y, a.z, a.w, bb.x, bb.y, bb.z, bb.w};

#pragma unroll
      for (int c = 0; c < 8; ++c) {
        float4 m0 = *(const float4*)&Mb[q * 64 + c * 8];
        float4 m1 = *(const float4*)&Mb[q * 64 + c * 8 + 4];
        acc[0] = fmaf(v[c], m0.x, acc[0]);
        acc[1] = fmaf(v[c], m0.y, acc[1]);
        acc[2] = fmaf(v[c], m0.z, acc[2]);
        acc[3] = fmaf(v[c], m0.w, acc[3]);
        acc[4] = fmaf(v[c], m1.x, acc[4]);
        acc[5] = fmaf(v[c], m1.y, acc[5]);
        acc[6] = fmaf(v[c], m1.z, acc[6]);
        acc[7] = fmaf(v[c], m1.w, acc[7]);
      }
    }
    __syncthreads();  // drains vmcnt (stage) before buffer reuse
  }
#undef STAGE

  float* dst = WT + ((size_t)k * N + i) * 8;
  *(float4*)(dst + 0) = make_float4(acc[0] * 0.125f, acc[1] * 0.125f,
                                    acc[2] * 0.125f, acc[3] * 0.125f);
  *(float4*)(dst + 4) = make_float4(acc[4] * 0.125f, acc[5] * 0.125f,
                                    acc[6] * 0.125f, acc[7] * 0.125f);
}

// ---------------------------------------------------------------------------
// Per-node precompute for out_mlp layer 0.
// ---------------------------------------------------------------------------
__global__ __launch_bounds__(256) void node_pre(
    const float* __restrict__ feat, const float* __restrict__ w0,
    const float* __restrict__ b0, float* __restrict__ preK,
    float* __restrict__ preI) {
  const int n = blockIdx.x * 256 + threadIdx.x;
  if (n >= N) return;
  float f[8];
  float4 f0 = ((const float4*)(feat + (size_t)n * 8))[0];
  float4 f1 = ((const float4*)(feat + (size_t)n * 8))[1];
  f[0] = f0.x; f[1] = f0.y; f[2] = f0.z; f[3] = f0.w;
  f[4] = f1.x; f[5] = f1.y; f[6] = f1.z; f[7] = f1.w;
#pragma unroll
  for (int o = 0; o < 32; ++o) {
    float sK = 0.f, sI = b0[o];
#pragma unroll
    for (int c = 0; c < 8; ++c) {
      sK = fmaf(w0[o * 33 + 16 + c], f[c], sK);
      sI = fmaf(w0[o * 33 + 24 + c], f[c], sI);
    }
    preK[n * 32 + o] = sK;
    preI[n * 32 + o] = sI;
  }
}

// ---------------------------------------------------------------------------
// Output MLP: x = [mtr1[i,k,:], mtr1[k,i,:], feat[k], feat[i], (i==k)]
// layer0 uses precomputed node partials; 16x16 (i,k) tile per block.
// ---------------------------------------------------------------------------
__global__ __launch_bounds__(256) void out_mlp(
    const float* __restrict__ mtr, const float* __restrict__ WT,
    const float* __restrict__ preK, const float* __restrict__ preI,
    const float* __restrict__ w0,
    const float* __restrict__ w1, const float* __restrict__ b1,
    const float* __restrict__ w2, const float* __restrict__ b2,
    const float* __restrict__ w3, const float* __restrict__ b3,
    float* __restrict__ out) {
  __shared__ float sK[16][33], sI[16][33];
  const int il = threadIdx.x & 15;
  const int kl = threadIdx.x >> 4;
  const int i = blockIdx.y * 16 + il;
  const int k = blockIdx.x * 16 + kl;

  {
    const int r = threadIdx.x >> 4;
    const int c2 = (threadIdx.x & 15) * 2;
    const float* gK = preK + ((size_t)blockIdx.x * 16 + r) * 32;
    const float* gI = preI + ((size_t)blockIdx.y * 16 + r) * 32;
    sK[r][c2] = gK[c2]; sK[r][c2 + 1] = gK[c2 + 1];
    sI[r][c2] = gI[c2]; sI[r][c2 + 1] = gI[c2 + 1];
  }
  __syncthreads();

  float x[16];
  {
    const float* p1 = WT + ((size_t)k * N + i) * 8;  // mtr1[i,k,:]
    const float* p2 = WT + ((size_t)i * N + k) * 8;  // mtr1[k,i,:]
    float4 a0 = ((const float4*)p1)[0], a1 = ((const float4*)p1)[1];
    float4 c0 = ((const float4*)p2)[0], c1 = ((const float4*)p2)[1];
    x[0] = a0.x; x[1] = a0.y; x[2] = a0.z; x[3] = a0.w;
    x[4] = a1.x; x[5] = a1.y; x[6] = a1.z; x[7] = a1.w;
    x[8] = c0.x; x[9] = c0.y; x[10] = c0.z; x[11] = c0.w;
    x[12] = c1.x; x[13] = c1.y; x[14] = c1.z; x[15] = c1.w;
  }
  const float eye = (i == k) ? 1.f : 0.f;

  float h[32];
#pragma unroll
  for (int o = 0; o < 32; ++o) {
    float acc = sK[kl][o] + sI[il][o];
    acc = fmaf(eye, w0[o * 33 + 32], acc);
#pragma unroll
    for (int c = 0; c < 16; ++c) acc = fmaf(w0[o * 33 + c], x[c], acc);
    h[o] = fmaxf(acc, 0.f);
  }

#pragma unroll 1
  for (int l = 0; l < 2; ++l) {
    const float* W = l ? w2 : w1;
    const float* B = l ? b2 : b1;
    float g[32];
#pragma unroll
    for (int o = 0; o < 32; ++o) {
      float acc = B[o];
#pragma unroll
      for (int c = 0; c < 32; ++c) acc = fmaf(W[o * 32 + c], h[c], acc);
      g[o] = fmaxf(acc, 0.f);
    }
#pragma unroll
    for (int o = 0; o < 32; ++o) h[o] = g[o];
  }

  const size_t idx = ((size_t)i * N + k) * 8;
  float r[8];
#pragma unroll
  for (int t = 0; t < 8; ++t) {
    float acc = b3[t];
#pragma unroll
    for (int c = 0; c < 32; ++c) acc = fmaf(w3[t * 32 + c], h[c], acc);
    r[t] = acc;
  }
  *(float4*)(out + idx + 0) = make_float4(mtr[idx + 0] + r[0], mtr[idx + 1] + r[1],
                                          mtr[idx + 2] + r[2], mtr[idx + 3] + r[3]);
  *(float4*)(out + idx + 4) = make_float4(mtr[idx + 4] + r[4], mtr[idx + 5] + r[5],
                                          mtr[idx + 6] + r[6], mtr[idx + 7] + r[7]);
}

// ---------------------------------------------------------------------------
extern "C" void kernel_launch(void* const* d_in, const int* in_sizes, int n_in,
                              void* d_out, int out_size, void* d_ws,
                              size_t ws_size, hipStream_t stream) {
  const float* mtr  = (const float*)d_in[0];
  const float* feat = (const float*)d_in[1];
  const int*   ei   = (const int*)d_in[2];
  const float* ea   = (const float*)d_in[3];
  const float* ew0 = (const float*)d_in[4];
  const float* eb0 = (const float*)d_in[5];
  const float* ew1 = (const float*)d_in[6];
  const float* eb1 = (const float*)d_in[7];
  const float* ew2 = (const float*)d_in[8];
  const float* eb2 = (const float*)d_in[9];
  const float* ew3 = (const float*)d_in[10];
  const float* eb3 = (const float*)d_in[11];
  const float* ow0 = (const float*)d_in[12];
  const float* ob0 = (const float*)d_in[13];
  const float* ow1 = (const float*)d_in[14];
  const float* ob1 = (const float*)d_in[15];
  const float* ow2 = (const float*)d_in[16];
  const float* ob2 = (const float*)d_in[17];
  const float* ow3 = (const float*)d_in[18];
  const float* ob3 = (const float*)d_in[19];
  float* out = (float*)d_out;

  char* ws = (char*)d_ws;
  float* Mlist = (float*)ws; ws += (size_t)(E + 16) * 64 * 4;  // 6.3 MB (+pad)
  float* mtrT  = (float*)ws; ws += (size_t)N * N * 8 * 4;      // 18.87 MB
  float* WT    = (float*)ws; ws += (size_t)N * N * 8 * 4;      // 18.87 MB
  int* winner  = (int*)ws;   ws += (size_t)N * N * 4;          // 2.36 MB
  int* deg     = (int*)ws;   ws += 1024 * 4;
  int* offs    = (int*)ws;   ws += 1024 * 4;
  int* curs    = (int*)ws;   ws += 1024 * 4;
  int* jlist   = (int*)ws;   ws += (size_t)E * 4;              // 98 KB
  int* epos    = (int*)ws;   ws += (size_t)E * 4;              // 98 KB
  float* preK  = (float*)ws; ws += (size_t)N * 32 * 4;         // 98 KB
  float* preI  = (float*)ws; ws += (size_t)N * 32 * 4;         // 98 KB

  hipMemsetAsync(winner, 0xFF, (size_t)N * N * 4, stream);  // -1
  hipMemsetAsync(deg, 0, 1024 * 4, stream);
  hipMemsetAsync(curs, 0, 1024 * 4, stream);

  edge_prep<<<E / 256, 256, 0, stream>>>(ei, winner, deg);
  scan_offs<<<1, N, 0, stream>>>(deg, offs);
  scatter_pos<<<E / 256, 256, 0, stream>>>(ei, winner, offs, curs, jlist, epos);
  transpose_mtr<<<dim3(48, 48), 256, 0, stream>>>(mtr, mtrT);
  node_pre<<<3, 256, 0, stream>>>(feat, ow0, ob0, preK, preI);
  edge_mlp<<<E / 256, 256, 0, stream>>>(feat, ei, ea, epos, ew0, eb0, ew1, eb1,
                                        ew2, eb2, ew3, eb3, Mlist);
  contract5<<<4608, 128, 0, stream>>>(mtrT, Mlist, jlist, offs, curs, WT);
  out_mlp<<<dim3(48, 48), 256, 0, stream>>>(mtr, WT, preK, preI, ow0, ow1, ob1,
                                            ow2, ob2, ow3, ob3, out);
}